// Round 5
// baseline (10116.401 us; speedup 1.0000x reference)
//
#include <hip/hip_runtime.h>
#include <cstdint>
#include <cstddef>

// ---------------------------------------------------------------------------
// Problem constants (ARU recurrence): B=32, S=1024, H=1024, 3H=3072
// ---------------------------------------------------------------------------
#define HID   1024
#define BATCH 32
#define SEQ   1024
#define NROWS 32768   /* BATCH*SEQ */
#define G3    3072
#define NWG   64      /* recurrence workgroups; each owns 16 h-columns */
#define FLSTR 1025    /* flag stride per chain (u32) */
#define NFLAGS (128 * FLSTR)

typedef __attribute__((ext_vector_type(8))) short bf16x8_t;
typedef __attribute__((ext_vector_type(4))) float f32x4_t;

__device__ __forceinline__ unsigned short f2bf(float f) {
  unsigned u = __float_as_uint(f);
  u += 0x7FFFu + ((u >> 16) & 1u);       // round-to-nearest-even
  return (unsigned short)(u >> 16);
}
__device__ __forceinline__ float bf2f(unsigned short s) {
  return __uint_as_float(((unsigned)s) << 16);
}

// write-through device-coherent 16-bit store (lands at IF$/fabric, not dirty
// in producer's private L2; consumers' first-touch plain loads see it)
__device__ __forceinline__ void store_short_wt(unsigned short* p, unsigned short v) {
  asm volatile("global_store_short %0, %1, off sc0 sc1"
               :: "v"(p), "v"((unsigned)v) : "memory");
}

// ---------------------------------------------------------------------------
// K0: transpose + cast  W (1024 x N) fp32  ->  WT (N x 1024) bf16
// ---------------------------------------------------------------------------
__global__ __launch_bounds__(256) void transpose_cast(const float* __restrict__ in,
                                                      unsigned short* __restrict__ out,
                                                      int N) {
  __shared__ float tile[32][33];
  int k0 = blockIdx.x * 32, n0 = blockIdx.y * 32;
  int tx = threadIdx.x, ty = threadIdx.y;   // (32,8)
#pragma unroll
  for (int i = 0; i < 4; ++i)
    tile[ty + 8 * i][tx] = in[(size_t)(k0 + ty + 8 * i) * N + n0 + tx];
  __syncthreads();
#pragma unroll
  for (int i = 0; i < 4; ++i)
    out[(size_t)(n0 + ty + 8 * i) * HID + k0 + tx] = f2bf(tile[tx][ty + 8 * i]);
}

// ---------------------------------------------------------------------------
// K1: e = bf16(embed[x])   (32768 x 1024)
// ---------------------------------------------------------------------------
__global__ __launch_bounds__(256) void gather_cast(const int* __restrict__ x,
                                                   const float* __restrict__ embed,
                                                   unsigned short* __restrict__ e) {
  int r = blockIdx.x;
  int t = threadIdx.x;
  int tok = x[r];
  const float4* src = (const float4*)(embed + (size_t)tok * HID);
  float4 v = src[t];
  ushort4 o;
  o.x = f2bf(v.x); o.y = f2bf(v.y); o.z = f2bf(v.z); o.w = f2bf(v.w);
  ((ushort4*)(e + (size_t)r * HID))[t] = o;
}

// ---------------------------------------------------------------------------
// K2: fused GEMM  C = e(32768x1024) @ B'(1024x4096)  [B' n-major (4096x1024)]
// Epilogue writes PERMUTED layouts for the recurrence:
//   gxp[((t*64+g)*1536) + gate*512 + b*16 + c]   (gate_x + bgx, bf16)
//   cndp[((t*64+g)*512) + b*16 + c]              (tanh(cand + bc), bf16)
// so each (t, WG) block is contiguous (1.5KB / 0.5KB) -> fetch == useful.
// ---------------------------------------------------------------------------
__global__ __launch_bounds__(256) void gemm_fused(const unsigned short* __restrict__ A,
                                                  const unsigned short* __restrict__ B,
                                                  const float* __restrict__ bgx,
                                                  const float* __restrict__ bc,
                                                  unsigned short* __restrict__ gxp,
                                                  unsigned short* __restrict__ cndp) {
  __shared__ unsigned short As[128 * 32];
  __shared__ unsigned short Bs[128 * 32];
  const int bm = blockIdx.x * 128, bn = blockIdx.y * 128;
  const int t = threadIdx.x;
  const int wave = t >> 6, lane = t & 63;
  const int q = lane >> 4, nidx = lane & 15;
  const int wm = (wave & 1) * 64, wn = (wave >> 1) * 64;
  const int sr = t >> 2;
  const int kofs = (t & 3) * 8;

  f32x4_t acc[4][4];
#pragma unroll
  for (int i = 0; i < 4; ++i)
#pragma unroll
    for (int j = 0; j < 4; ++j) acc[i][j] = (f32x4_t){0.f, 0.f, 0.f, 0.f};

#pragma unroll 1
  for (int kt = 0; kt < HID; kt += 32) {
    __syncthreads();
#pragma unroll
    for (int c = 0; c < 2; ++c) {
      int row = c * 64 + sr;
      *(uint4*)(&As[row * 32 + kofs]) = *(const uint4*)(&A[(size_t)(bm + row) * HID + kt + kofs]);
      *(uint4*)(&Bs[row * 32 + kofs]) = *(const uint4*)(&B[(size_t)(bn + row) * HID + kt + kofs]);
    }
    __syncthreads();
    bf16x8_t af[4], bfr[4];
#pragma unroll
    for (int i = 0; i < 4; ++i)
      af[i] = *(const bf16x8_t*)(&As[(wm + i * 16 + nidx) * 32 + q * 8]);
#pragma unroll
    for (int j = 0; j < 4; ++j)
      bfr[j] = *(const bf16x8_t*)(&Bs[(wn + j * 16 + nidx) * 32 + q * 8]);
#pragma unroll
    for (int i = 0; i < 4; ++i)
#pragma unroll
      for (int j = 0; j < 4; ++j)
        acc[i][j] = __builtin_amdgcn_mfma_f32_16x16x32_bf16(af[i], bfr[j], acc[i][j], 0, 0, 0);
  }

#pragma unroll
  for (int i = 0; i < 4; ++i) {
#pragma unroll
    for (int j = 0; j < 4; ++j) {
#pragma unroll
      for (int reg = 0; reg < 4; ++reg) {
        int m = bm + wm + i * 16 + q * 4 + reg;
        int n = bn + wn + j * 16 + nidx;
        int b = m >> 10, tt = m & 1023;   // e row = b*SEQ + t
        float v = acc[i][j][reg];
        if (n < G3) {
          int gate = n >> 10, colw = n & 1023, g2 = colw >> 4, c = colw & 15;
          gxp[((size_t)tt * NWG + g2) * 1536 + gate * 512 + b * 16 + c] = f2bf(v + bgx[n]);
        } else {
          int cw = n - G3, g2 = cw >> 4, c = cw & 15;
          cndp[((size_t)tt * NWG + g2) * 512 + b * 16 + c] = f2bf(tanhf(v + bc[cw]));
        }
      }
    }
  }
}

// ---------------------------------------------------------------------------
// K3a: init flags + zero h ring slot 0.
// 128 chains (g, wave) each with stride FLSTR; flags[p*FLSTR + 0] = 1.
// ---------------------------------------------------------------------------
__global__ __launch_bounds__(256) void init_state(unsigned int* __restrict__ flags,
                                                  unsigned short* __restrict__ ring) {
  int t = blockIdx.x * 256 + threadIdx.x;   // grid 513*256 = 131328 >= NFLAGS
  if (t < NFLAGS) {
    int rem = t - (t / FLSTR) * FLSTR;
    flags[t] = (rem == 0) ? 1u : 0u;
  }
  if (t < BATCH * HID) ring[t] = 0;
}

// ---------------------------------------------------------------------------
// K3: recurrence. 64 WGs x 128 thr. WG g owns h-cols [16g,16g+16).
// Wave w = independent chain for batch rows [16w,16w+16) — NO syncthreads in
// the step loop. LDS: rho|pi B-tiles (32x1024 bf16, 64KB, XOR-swizzled);
// alpha B-frags stream from global WghT (32KB/WG slice, L2-resident).
// All 3 gates for col 16g+n live in lane n — no shuffles.
// Exchange: write-through sc1 h stores -> vmcnt(0) -> per-chain flag store;
// consumers poll their chain's 64 producer flags (1 per lane), then plain
// cached loads (write-once ring; one acquire fence before the loop).
// ---------------------------------------------------------------------------
__global__ __launch_bounds__(128) void recurrence(const unsigned short* __restrict__ gxp,
                                                  const unsigned short* __restrict__ cndp,
                                                  const unsigned short* __restrict__ WghT,
                                                  unsigned short* __restrict__ ring,
                                                  unsigned int* __restrict__ flags,
                                                  float* __restrict__ out) {
  const int g = blockIdx.x;          // owns h-cols [16g, 16g+16)
  const int tid = threadIdx.x;
  const int w = tid >> 6;            // chain = batch half
  const int lane = tid & 63;
  const int q = lane >> 4, n = lane & 15;

  __shared__ __align__(16) unsigned short Bs[32 * 1024];   // 64 KB: rho|pi

  // stage rho+pi Wgh^T slices, XOR-swizzled in 16B units
  for (int it = tid; it < 4096; it += 128) {
    int row = it >> 7, c16 = it & 127;
    int gr = (row < 16) ? (16 * g + row) : (1024 + 16 * g + (row - 16));
    uint4 val = ((const uint4*)(WghT + (size_t)gr * HID))[c16];
    *(uint4*)((char*)Bs + (size_t)(row * 128 + (c16 ^ (row & 7))) * 16) = val;
  }
  __syncthreads();

  // ONE L2 invalidate for the whole kernel (ring aliases e's stale lines)
  __builtin_amdgcn_fence(__ATOMIC_ACQUIRE, "agent");

  float h_own[4] = {0.f, 0.f, 0.f, 0.f};
  const char* b0p = (const char*)Bs + (size_t)n * 2048;          // rho row n
  const char* b1p = b0p + 16 * 2048;                              // pi row n
  const unsigned short* alphaW = WghT + (size_t)(2048 + 16 * g + n) * HID + q * 8;
  const unsigned int* fpoll = flags + (size_t)(lane * 2 + w) * FLSTR;
  const int c_h = 16 * g + n;

#pragma unroll 1
  for (int t = 0; t < SEQ; ++t) {
    const unsigned short* hc = ring + ((size_t)t << 15);
    unsigned short* hn = ring + ((size_t)(t + 1) << 15);

    // prefetch this step's contiguous gate blocks (hidden behind the poll)
    const unsigned short* gblk = gxp + ((size_t)t * NWG + g) * 1536;
    const unsigned short* cblk = cndp + ((size_t)t * NWG + g) * 512;
    float g0v[4], g1v[4], g2v[4], vv[4];
#pragma unroll
    for (int r = 0; r < 4; ++r) {
      int b = w * 16 + q * 4 + r;
      g0v[r] = bf2f(gblk[b * 16 + n]);
      g1v[r] = bf2f(gblk[512 + b * 16 + n]);
      g2v[r] = bf2f(gblk[1024 + b * 16 + n]);
      vv[r]  = bf2f(cblk[b * 16 + n]);
    }

    // chain barrier: lane l waits for producer WG l (same wave-chain)
    while (__hip_atomic_load(&fpoll[t], __ATOMIC_RELAXED, __HIP_MEMORY_SCOPE_AGENT) == 0u) {}
    asm volatile("" ::: "memory");   // pin h loads after the poll

    // preact = h(t) @ Wgh cols [16g..16g+16) for rho/pi (LDS) + alpha (L2)
    f32x4_t acc0 = (f32x4_t){0.f, 0.f, 0.f, 0.f};
    f32x4_t acc1 = (f32x4_t){0.f, 0.f, 0.f, 0.f};
    f32x4_t acc2 = (f32x4_t){0.f, 0.f, 0.f, 0.f};
    const unsigned short* ha = hc + (size_t)(w * 16 + n) * HID + q * 8;
#pragma unroll 8
    for (int kt = 0; kt < 32; ++kt) {
      bf16x8_t a = *(const bf16x8_t*)(ha + kt * 32);
      int sw = ((kt * 4 + q) ^ (n & 7)) * 16;
      bf16x8_t b0 = *(const bf16x8_t*)(b0p + sw);
      bf16x8_t b1 = *(const bf16x8_t*)(b1p + sw);
      bf16x8_t b2 = *(const bf16x8_t*)(alphaW + kt * 32);
      acc0 = __builtin_amdgcn_mfma_f32_16x16x32_bf16(a, b0, acc0, 0, 0, 0);
      acc1 = __builtin_amdgcn_mfma_f32_16x16x32_bf16(a, b1, acc1, 0, 0, 0);
      acc2 = __builtin_amdgcn_mfma_f32_16x16x32_bf16(a, b2, acc2, 0, 0, 0);
    }

    // gates + carry: all three gates in-lane. D: col=n, row(batch)=q*4+r.
#pragma unroll
    for (int r = 0; r < 4; ++r) {
      float rho = 1.f / (1.f + __expf(-(acc0[r] + g0v[r])));
      float pi  = 1.f / (1.f + __expf(-(acc1[r] + g1v[r])));
      float al  = 1.f / (1.f + __expf(-(acc2[r] + g2v[r])));
      h_own[r] = rho * (pi * h_own[r] + al * vv[r]);
      store_short_wt(&hn[(size_t)(w * 16 + q * 4 + r) * HID + c_h], f2bf(h_own[r]));
    }

    // publish: drain this wave's stores to fabric, then one flag per chain
    asm volatile("s_waitcnt vmcnt(0)" ::: "memory");
    if (lane == 0)
      __hip_atomic_store(&flags[(size_t)(g * 2 + w) * FLSTR + t + 1], 1u,
                         __ATOMIC_RELAXED, __HIP_MEMORY_SCOPE_AGENT);
  }

#pragma unroll
  for (int r = 0; r < 4; ++r)
    out[(size_t)(w * 16 + q * 4 + r) * HID + c_h] = h_own[r];
}

// ---------------------------------------------------------------------------
// launcher
// ---------------------------------------------------------------------------
extern "C" void kernel_launch(void* const* d_in, const int* in_sizes, int n_in,
                              void* d_out, int out_size, void* d_ws, size_t ws_size,
                              hipStream_t stream) {
  const int*   x     = (const int*)d_in[0];
  const float* embed = (const float*)d_in[1];
  const float* Wc    = (const float*)d_in[2];
  const float* bc    = (const float*)d_in[3];
  const float* Wgx   = (const float*)d_in[4];
  const float* bgx   = (const float*)d_in[5];
  const float* Wgh   = (const float*)d_in[6];
  float* out = (float*)d_out;

  char* base = (char*)d_ws;
  unsigned short* e    = (unsigned short*)(base);                       // 32768x1024 bf16 = 64 MiB
  unsigned short* Bp   = (unsigned short*)(base + 67108864);            // 4096x1024 bf16  = 8 MiB
  unsigned short* WghT = (unsigned short*)(base + 75497472);            // 3072x1024 bf16  = 6 MiB
  unsigned short* gxp  = (unsigned short*)(base + 81788928);            // 1024x64x1536 bf16 = 192 MiB
  unsigned short* cndp = (unsigned short*)(base + 283115520);           // 1024x64x512 bf16  = 64 MiB
  // h ring: 1025 slots x 64 KB = 67,174,400 B, aliases e (dead after gemm)
  unsigned short* ring  = (unsigned short*)(base);
  // flags: 128 chains x 1025 u32 = 524,800 B in dead Bp zone (after ring end)
  unsigned int*   flags = (unsigned int*)(base + 70000000);

  transpose_cast<<<dim3(32, 96), dim3(32, 8), 0, stream>>>(Wgx, Bp, G3);
  transpose_cast<<<dim3(32, 32), dim3(32, 8), 0, stream>>>(Wc, Bp + (size_t)G3 * HID, HID);
  transpose_cast<<<dim3(32, 96), dim3(32, 8), 0, stream>>>(Wgh, WghT, G3);

  gather_cast<<<dim3(NROWS), dim3(256), 0, stream>>>(x, embed, e);

  gemm_fused<<<dim3(256, 32), dim3(256), 0, stream>>>(e, Bp, bgx, bc, gxp, cndp);

  // init flags + ring slot 0 AFTER gemm (ring/flags alias gemm-era storage)
  init_state<<<dim3(513), dim3(256), 0, stream>>>(flags, ring);

  void* args[] = {(void*)&gxp, (void*)&cndp, (void*)&WghT, (void*)&ring,
                  (void*)&flags, (void*)&out};
  hipLaunchCooperativeKernel((const void*)recurrence, dim3(NWG), dim3(128), args, 0, stream);
}